// Round 8
// baseline (327.290 us; speedup 1.0000x reference)
//
#include <hip/hip_runtime.h>
#include <math.h>

#define BB 4
#define TT 2048
#define VV 1024
#define CC 256
#define MR (BB*TT)   // 8192 rows

using short8  = __attribute__((ext_vector_type(8))) short;
using ushort8 = __attribute__((ext_vector_type(8))) unsigned short;
using f32x4   = __attribute__((ext_vector_type(4))) float;

__device__ __forceinline__ float bs2f(unsigned short s) {
    return __uint_as_float(((unsigned int)s) << 16);
}
__device__ __forceinline__ unsigned short f2bs(float f) {
    unsigned int u = __float_as_uint(f);
    u += 0x7fffu + ((u >> 16) & 1u);          // round-to-nearest-even
    return (unsigned short)(u >> 16);
}
__device__ __forceinline__ void gl_lds16(const void* g, void* l) {
    __builtin_amdgcn_global_load_lds(
        (const __attribute__((address_space(1))) unsigned int*)g,
        (__attribute__((address_space(3))) unsigned int*)l, 16, 0, 0);
}
__device__ __forceinline__ float sigm(float x) { return 1.f / (1.f + expf(-x)); }

// ---------------------------------------------------------------------------
// Fused multi-array fp32 -> bf16 cast (coalesced). grid = (njobs, 64)
struct CastJob { const float* src; unsigned short* dst; int n; };
struct CastArgs { CastJob j[17]; };

__global__ void cast_bf16_multi(CastArgs a) {
    CastJob jb = a.j[blockIdx.x];
    int off = (blockIdx.y * 256 + threadIdx.x) * 8;
    if (off + 8 > jb.n) return;
    float4 v0 = *reinterpret_cast<const float4*>(jb.src + off);
    float4 v1 = *reinterpret_cast<const float4*>(jb.src + off + 4);
    ushort8 u;
    u[0] = f2bs(v0.x); u[1] = f2bs(v0.y); u[2] = f2bs(v0.z); u[3] = f2bs(v0.w);
    u[4] = f2bs(v1.x); u[5] = f2bs(v1.y); u[6] = f2bs(v1.z); u[7] = f2bs(v1.w);
    *reinterpret_cast<ushort8*>(jb.dst + off) = u;
}

// Row softmax in place over [rows][1024] bf16. grid = rows, block = 256.
__global__ void softmax_rows(unsigned short* __restrict__ w) {
    int r = blockIdx.x, t = threadIdx.x;
    unsigned short* row = w + (size_t)r * 1024;
    ushort4 u = reinterpret_cast<ushort4*>(row)[t];
    float v0 = bs2f(u.x), v1 = bs2f(u.y), v2 = bs2f(u.z), v3 = bs2f(u.w);
    __shared__ float red[256];
    red[t] = fmaxf(fmaxf(v0, v1), fmaxf(v2, v3));
    __syncthreads();
    for (int o = 128; o > 0; o >>= 1) { if (t < o) red[t] = fmaxf(red[t], red[t + o]); __syncthreads(); }
    float mx = red[0]; __syncthreads();
    float e0 = expf(v0 - mx), e1 = expf(v1 - mx), e2 = expf(v2 - mx), e3 = expf(v3 - mx);
    red[t] = e0 + e1 + e2 + e3;
    __syncthreads();
    for (int o = 128; o > 0; o >>= 1) { if (t < o) red[t] += red[t + o]; __syncthreads(); }
    float inv = 1.f / red[0];
    ushort4 o4;
    o4.x = f2bs(e0 * inv); o4.y = f2bs(e1 * inv); o4.z = f2bs(e2 * inv); o4.w = f2bs(e3 * inv);
    reinterpret_cast<ushort4*>(row)[t] = o4;
}

// 5x fused 256x256 fp32->bf16 transpose. grid = (256,5)
__global__ void prep_T5(const float* s0, const float* s1, const float* s2,
                        const float* s3, const float* s4,
                        unsigned short* d0, unsigned short* d1, unsigned short* d2,
                        unsigned short* d3, unsigned short* d4) {
    int y = blockIdx.y;
    const float* W = y == 0 ? s0 : y == 1 ? s1 : y == 2 ? s2 : y == 3 ? s3 : s4;
    unsigned short* WT = y == 0 ? d0 : y == 1 ? d1 : y == 2 ? d2 : y == 3 ? d3 : d4;
    int n = blockIdx.x, k = threadIdx.x;
    WT[(size_t)n * 256 + k] = f2bs(W[(size_t)k * 256 + n]);
}

// ---------------------------------------------------------------------------
// RMS norm: one block per row (V=1024), bf16 out
__global__ void rmsnorm_k(const float* __restrict__ x, unsigned short* __restrict__ xn) {
    int row = blockIdx.x, t = threadIdx.x;
    const float4 v = reinterpret_cast<const float4*>(x + (size_t)row * VV)[t];
    __shared__ float red[256];
    red[t] = v.x * v.x + v.y * v.y + v.z * v.z + v.w * v.w;
    __syncthreads();
    for (int o = 128; o > 0; o >>= 1) { if (t < o) red[t] += red[t + o]; __syncthreads(); }
    float r = rsqrtf(red[0] * (1.f / VV) + 1.1920929e-7f);
    ushort4 u;
    u.x = f2bs(v.x * r); u.y = f2bs(v.y * r); u.z = f2bs(v.z * r); u.w = f2bs(v.w * r);
    reinterpret_cast<ushort4*>(xn + (size_t)row * VV)[t] = u;
}

// ---------------------------------------------------------------------------
// 4-in-1 bf16 transpose of qkv slices: V^T (plain) and K^T (decay-scaled).
// grid (64, 8, 16): z -> (which = z>>2, b = z&3)
__global__ void transpose4_k(const unsigned short* __restrict__ qkv,
                             unsigned short* __restrict__ vt_s,
                             unsigned short* __restrict__ vt_f,
                             unsigned short* __restrict__ kts_s,
                             unsigned short* __restrict__ kts_f,
                             const float* __restrict__ dls,
                             const float* __restrict__ dlf) {
    __shared__ unsigned short tile[32][33];
    int z = blockIdx.z, b = z & 3, which = z >> 2;
    int srcoff = which == 0 ? 512 : which == 1 ? 1280 : which == 2 ? 256 : 1024;
    unsigned short* dst = which == 0 ? vt_s : which == 1 ? vt_f : which == 2 ? kts_s : kts_f;
    float l2d = 0.f;
    if (which == 2) l2d = log2f(sigm(dls[0]));
    if (which == 3) l2d = log2f(sigm(dlf[0]));
    int t0 = blockIdx.x * 32, c0 = blockIdx.y * 32;
    int tx = threadIdx.x & 31, ty = threadIdx.x >> 5;
    const unsigned short* src = qkv + srcoff;
    #pragma unroll
    for (int i = 0; i < 4; ++i) {
        int r = ty + i * 8;
        tile[r][tx] = src[(size_t)(b * TT + t0 + r) * 1536 + c0 + tx];
    }
    __syncthreads();
    float w = (which >= 2) ? exp2f(l2d * (float)((t0 + tx) & 127)) : 1.f;
    #pragma unroll
    for (int i = 0; i < 4; ++i) {
        int r = ty + i * 8;
        dst[((size_t)b * CC + c0 + r) * TT + t0 + tx] = f2bs(bs2f(tile[tx][r]) * w);
    }
}

// ---------------------------------------------------------------------------
// Shared 64x64 GEMM core: acc = A[m0..+64, :K] * Bt[n0..+64, :K]^T
__device__ __forceinline__ void gemm64_core(
    const unsigned short* A, int lda, const unsigned short* Bt, int ldb,
    int K, int m0, int n0, short8* As, short8* Bs, f32x4 (&acc)[2][2]) {
    const int tid = threadIdx.x;
    const int lane = tid & 63, wid = tid >> 6;
    const int wm = wid >> 1, wn = wid & 1;
    const int lrow = tid >> 2, lch = tid & 3;
    const int sws = lch ^ ((lrow >> 1) & 3);
    const unsigned short* ag = A + (size_t)(m0 + lrow) * lda + lch * 8;
    const unsigned short* bg = Bt + (size_t)(n0 + lrow) * ldb + lch * 8;
    #pragma unroll
    for (int i = 0; i < 2; ++i)
        #pragma unroll
        for (int j = 0; j < 2; ++j) acc[i][j] = {0.f, 0.f, 0.f, 0.f};
    const int g = lane >> 4;
    const int ra0 = wm * 32 + (lane & 15);
    const int rb0 = wn * 32 + (lane & 15);
    for (int k0 = 0; k0 < K; k0 += 32) {
        As[lrow * 4 + sws] = *reinterpret_cast<const short8*>(ag + k0);
        Bs[lrow * 4 + sws] = *reinterpret_cast<const short8*>(bg + k0);
        __syncthreads();
        short8 af[2], bf[2];
        #pragma unroll
        for (int i = 0; i < 2; ++i) {
            int ra = ra0 + i * 16;
            af[i] = As[ra * 4 + (g ^ ((ra >> 1) & 3))];
            int rb = rb0 + i * 16;
            bf[i] = Bs[rb * 4 + (g ^ ((rb >> 1) & 3))];
        }
        #pragma unroll
        for (int i = 0; i < 2; ++i)
            #pragma unroll
            for (int j = 0; j < 2; ++j)
                acc[i][j] = __builtin_amdgcn_mfma_f32_16x16x32_bf16(af[i], bf[j], acc[i][j], 0, 0, 0);
        __syncthreads();
    }
}

// epilogue index helpers (per thread)
#define EPI_LOOP(MV, NV, VV_, BODY)                                            \
    {   const int lane_ = threadIdx.x & 63, wid_ = threadIdx.x >> 6;           \
        const int wm_ = wid_ >> 1, wn_ = wid_ & 1;                             \
        _Pragma("unroll")                                                      \
        for (int i_ = 0; i_ < 2; ++i_)                                         \
        { _Pragma("unroll")                                                    \
          for (int j_ = 0; j_ < 2; ++j_)                                       \
          { _Pragma("unroll")                                                  \
            for (int r_ = 0; r_ < 4; ++r_)                                     \
            { int MV = m0 + wm_ * 32 + i_ * 16 + (lane_ >> 4) * 4 + r_;        \
              int NV = n0 + wn_ * 32 + j_ * 16 + (lane_ & 15);                 \
              float VV_ = acc[i_][j_][r_];                                     \
              BODY } } } }

// ---------------------------------------------------------------------------
// Multi-job 64^2 GEMM. EPI 0: plain bf16 store; 4: scaled bf16 store.
struct MJob {
    const unsigned short* A; const unsigned short* Bt; unsigned short* outb;
    const float* s1; const float* s2;
    int lda, ldb, K, ldo, gx, nblk;
};
struct MJobs5 { MJob j[5]; };

template<int EPI>
__global__ __launch_bounds__(256)
void gemm_multi_k(MJobs5 js) {
    int bid = blockIdx.x, ji = 0, base = 0;
    while (bid >= base + js.j[ji].nblk) { base += js.j[ji].nblk; ++ji; }
    MJob jb = js.j[ji];
    int rem = bid - base;
    int m0 = (rem / jb.gx) * 64, n0 = (rem % jb.gx) * 64;
    __shared__ short8 As[256], Bs[256];
    f32x4 acc[2][2];
    gemm64_core(jb.A, jb.lda, jb.Bt, jb.ldb, jb.K, m0, n0, As, Bs, acc);
    float sc = 1.f;
    if constexpr (EPI == 4) sc = jb.s1[0] * jb.s2[0];
    EPI_LOOP(m, n, v, { jb.outb[(size_t)m * jb.ldo + n] = f2bs(v * sc); })
}

// sigmoid(acc+bias)*aux epilogue GEMM (K=256, ldb=256). grid (4,128)
__global__ __launch_bounds__(256)
void sig_k(const unsigned short* A, int lda, const unsigned short* Bt,
           const float* bias, const unsigned short* aux, int ldaux,
           unsigned short* outb, int ldo, int coloff) {
    int m0 = blockIdx.y * 64, n0 = blockIdx.x * 64;
    __shared__ short8 As[256], Bs[256];
    f32x4 acc[2][2];
    gemm64_core(A, lda, Bt, 256, 256, m0, n0, As, Bs, acc);
    EPI_LOOP(m, n, v, {
        float s = sigm(v + bias[n]);
        float a = bs2f(aux[(size_t)m * ldaux + n]);
        outb[(size_t)m * ldo + coloff + n] = f2bs(s * a);
    })
}

// 3x gelu(z@mix+bias) batched over z. grid (4,128,3)
__global__ __launch_bounds__(256)
void gelu3_k(const unsigned short* zbuf, const unsigned short* WT_mix,
             const float* lb, const float* mb, const float* hb,
             unsigned short* hcat, unsigned short* hhigh) {
    int zi = blockIdx.z;
    const unsigned short* A = zbuf + zi * 256;
    const unsigned short* Bt = WT_mix + (size_t)zi * 65536;
    const float* bias = zi == 0 ? lb : zi == 1 ? mb : hb;
    unsigned short* outb = zi == 2 ? hhigh : hcat;
    int ldo = zi == 2 ? 256 : 768;
    int coloff = zi == 1 ? 256 : 0;
    int m0 = blockIdx.y * 64, n0 = blockIdx.x * 64;
    __shared__ short8 As[256], Bs[256];
    f32x4 acc[2][2];
    gemm64_core(A, 768, Bt, 256, 256, m0, n0, As, Bs, acc);
    EPI_LOOP(m, n, v, {
        float z = v + bias[n];
        float h = 0.5f * z * (1.f + erff(z * 0.70710678118654752f));
        outb[(size_t)m * ldo + coloff + n] = f2bs(h);
    })
}

// chunk states G = (scaled K)^T @ V per (b,chunk,band). grid (4,4,128)
__global__ __launch_bounds__(256)
void gstate_k(const unsigned short* kts_s, const unsigned short* vt_s,
              const unsigned short* kts_f, const unsigned short* vt_f,
              float* Gs, float* Gf) {
    int zz = blockIdx.z;
    int sel = zz >> 6, z2 = zz & 63;
    int zb = z2 >> 4, zp = z2 & 15;
    const unsigned short* A  = (sel ? kts_f : kts_s) + (size_t)(zb * CC) * TT + zp * 128;
    const unsigned short* Bt = (sel ? vt_f  : vt_s)  + (size_t)(zb * CC) * TT + zp * 128;
    float* G = (sel ? Gf : Gs) + (size_t)z2 * 65536;
    int m0 = blockIdx.y * 64, n0 = blockIdx.x * 64;
    __shared__ short8 As[256], Bs[256];
    f32x4 acc[2][2];
    gemm64_core(A, TT, Bt, TT, 128, m0, n0, As, Bs, acc);
    EPI_LOOP(m, n, v, { G[(size_t)m * 256 + n] = v; })
}

// inter-chunk: r += d^(127-m) * Q_chunk @ S. grid (4,2,120): z<60 slow.
__global__ __launch_bounds__(256)
void inter_k(const unsigned short* qkv,
             const unsigned short* ST_s, const unsigned short* ST_f,
             const float* dls, const float* dlf,
             unsigned short* rcat, unsigned short* rfast) {
    int zz = blockIdx.z;
    int sel = zz >= 60, z2 = sel ? zz - 60 : zz;
    int zb = z2 / 15, zp = z2 % 15;
    const unsigned short* A = qkv + (sel ? 768 : 0) + (size_t)(zb * TT + zp * 128) * 1536;
    const unsigned short* Bt = (sel ? ST_f : ST_s) + (size_t)z2 * 65536;
    unsigned short* outb = sel ? rfast : rcat;
    int ldo = sel ? 256 : 512;
    float l2d = log2f(sigm(sel ? dlf[0] : dls[0]));
    int m0 = blockIdx.y * 64, n0 = blockIdx.x * 64;
    __shared__ short8 As[256], Bs[256];
    f32x4 acc[2][2];
    gemm64_core(A, 1536, Bt, 256, 256, m0, n0, As, Bs, acc);
    EPI_LOOP(m, n, v, {
        float rs = exp2f(l2d * (float)(127 - m));
        size_t idx = (size_t)(zb * TT + zp * 128 + m) * ldo + n;
        outb[idx] = f2bs(bs2f(outb[idx]) + v * rs);
    })
}

// ---------------------------------------------------------------------------
// 128x128 GEMM, BK=64, double-buffered global_load_lds with counted vmcnt,
// XCD-swizzled grid (ngw % 8 == 0). EPI 0: bf16 store; 3: fp32 out = addf+acc.
struct EpiP {
    float* outf; const float* addf;
    unsigned short* outb; int ldo;
};

template<int EPI>
__global__ __launch_bounds__(256)
void gemm128_k(const unsigned short* __restrict__ A, int lda,
               const unsigned short* __restrict__ Bt, int ldb, int K, EpiP ep) {
    __shared__ short8 As[2][1024], Bs[2][1024];    // 2 buf x 128 rows x 8 chunks
    const int tid = threadIdx.x;
    const int lane = tid & 63, wid = tid >> 6;
    const int wm = wid >> 1, wn = wid & 1;

    int lin = blockIdx.y * gridDim.x + blockIdx.x;
    int ngw = gridDim.x * gridDim.y;
    int q8 = ngw >> 3;
    int sw = (lin & 7) * q8 + (lin >> 3);
    const int m0 = (sw / gridDim.x) * 128, n0 = (sw % gridDim.x) * 128;

    const int srow = lane >> 3, schk = (lane & 7) ^ srow;
    const unsigned short* ga = A + (size_t)(m0 + wid * 32 + srow) * lda + schk * 8;
    const unsigned short* gb = Bt + (size_t)(n0 + wid * 32 + srow) * ldb + schk * 8;

    const int fr = lane & 15, fg = lane >> 4;

    f32x4 acc[4][4];
    #pragma unroll
    for (int i = 0; i < 4; ++i)
        #pragma unroll
        for (int j = 0; j < 4; ++j) acc[i][j] = {0.f, 0.f, 0.f, 0.f};

    auto stage = [&](int buf, int k0) {
        short8* lA = &As[buf][(wid * 32) * 8];
        short8* lB = &Bs[buf][(wid * 32) * 8];
        #pragma unroll
        for (int q = 0; q < 4; ++q) {
            gl_lds16(ga + (size_t)(q * 8) * lda + k0, lA + q * 64);
            gl_lds16(gb + (size_t)(q * 8) * ldb + k0, lB + q * 64);
        }
    };

    stage(0, 0);
    int cur = 0;
    for (int k0 = 0; k0 < K; k0 += 64) {
        if (k0 + 64 < K) {
            stage(cur ^ 1, k0 + 64);                         // 8 loads in flight
            asm volatile("s_waitcnt vmcnt(8)" ::: "memory"); // prev 8 (cur buf) done
        } else {
            asm volatile("s_waitcnt vmcnt(0)" ::: "memory");
        }
        __builtin_amdgcn_s_barrier();
        __builtin_amdgcn_sched_barrier(0);
        #pragma unroll
        for (int kk = 0; kk < 2; ++kk) {
            short8 af[4], bf[4];
            #pragma unroll
            for (int i = 0; i < 4; ++i) {
                int ra = wm * 64 + i * 16 + fr;
                af[i] = As[cur][ra * 8 + ((kk * 4 + fg) ^ (ra & 7))];
                int rb = wn * 64 + i * 16 + fr;
                bf[i] = Bs[cur][rb * 8 + ((kk * 4 + fg) ^ (rb & 7))];
            }
            #pragma unroll
            for (int i = 0; i < 4; ++i)
                #pragma unroll
                for (int j = 0; j < 4; ++j)
                    acc[i][j] = __builtin_amdgcn_mfma_f32_16x16x32_bf16(af[i], bf[j], acc[i][j], 0, 0, 0);
        }
        __builtin_amdgcn_sched_barrier(0);
        __builtin_amdgcn_s_barrier();                        // readers done before overwrite
        cur ^= 1;
    }

    #pragma unroll
    for (int i = 0; i < 4; ++i) {
        #pragma unroll
        for (int j = 0; j < 4; ++j) {
            #pragma unroll
            for (int r = 0; r < 4; ++r) {
                int m = m0 + wm * 64 + i * 16 + fg * 4 + r;
                int n = n0 + wn * 64 + j * 16 + fr;
                float v = acc[i][j][r];
                if constexpr (EPI == 0) {
                    ep.outb[(size_t)m * ep.ldo + n] = f2bs(v);
                } else {
                    size_t idx = (size_t)m * ep.ldo + n;
                    ep.outf[idx] = ep.addf[idx] + v;
                }
            }
        }
    }
}

// ---------------------------------------------------------------------------
// Intra-chunk decay retrieval; slow (y=0) and fast (y=1) merged in one grid.
__global__ __launch_bounds__(256)
void attn_k(const unsigned short* __restrict__ qkv,
            const unsigned short* __restrict__ vt_s,
            const unsigned short* __restrict__ vt_f,
            const float* __restrict__ dls, const float* __restrict__ dlf,
            unsigned short* __restrict__ rcat, unsigned short* __restrict__ rfast) {
    int y = blockIdx.y;
    int qoff = y ? 768 : 0, koff = y ? 1024 : 256;
    const unsigned short* vt = y ? vt_f : vt_s;
    unsigned short* rout = y ? rfast : rcat;
    int ldr = y ? 256 : 512;
    float l2d = log2f(sigm(y ? dlf[0] : dls[0]));

    int blk = blockIdx.x;
    int b = blk >> 7;
    int t0 = (blk & 127) << 4;
    int tid = threadIdx.x;
    int lane = tid & 63, wid = tid >> 6;

    __shared__ short8 Pl[4][64];
    __shared__ float  red[16][260];

    short8 qf[8];
    const size_t rowq = (size_t)(b * TT + t0 + (lane & 15)) * 1536 + qoff + (lane >> 4) * 8;
    #pragma unroll
    for (int ch = 0; ch < 8; ++ch)
        qf[ch] = *reinterpret_cast<const short8*>(qkv + rowq + ch * 32);

    f32x4 racc[16];
    #pragma unroll
    for (int i = 0; i < 16; ++i) racc[i] = {0.f, 0.f, 0.f, 0.f};

    unsigned short* pb = reinterpret_cast<unsigned short*>(&Pl[wid][0]);

    int sBeg = t0 & ~31;
    int sEnd = (t0 & ~127) + 128;
    const int tl = (lane >> 4) * 4;

    for (int s0 = sBeg + wid * 32; s0 < sEnd; s0 += 128) {
        #pragma unroll
        for (int h = 0; h < 2; ++h) {
            f32x4 sacc = {0.f, 0.f, 0.f, 0.f};
            const unsigned short* kb =
                qkv + (size_t)(b * TT + s0 + h * 16 + (lane & 15)) * 1536 + koff + (lane >> 4) * 8;
            #pragma unroll
            for (int ch = 0; ch < 8; ++ch) {
                short8 kf = *reinterpret_cast<const short8*>(kb + ch * 32);
                sacc = __builtin_amdgcn_mfma_f32_16x16x32_bf16(qf[ch], kf, sacc, 0, 0, 0);
            }
            int scol = s0 + h * 16 + (lane & 15);
            #pragma unroll
            for (int r = 0; r < 4; ++r) {
                int trow = t0 + tl + r;
                int d = scol - trow;
                float w = (d > 0) ? exp2f(l2d * (float)(d - 1)) : 0.f;
                int prow = tl + r, pcol = h * 16 + (lane & 15);
                int swp = (pcol >> 3) ^ ((prow >> 1) & 3);
                pb[(prow * 4 + swp) * 8 + (pcol & 7)] = f2bs(sacc[r] * w);
            }
        }
        asm volatile("s_waitcnt lgkmcnt(0)" ::: "memory");
        __builtin_amdgcn_sched_barrier(0);
        short8 pf;
        { int prow = lane & 15; pf = Pl[wid][prow * 4 + ((lane >> 4) ^ ((prow >> 1) & 3))]; }
        const unsigned short* vb = vt + ((size_t)b * CC + (lane & 15)) * TT + s0 + (lane >> 4) * 8;
        #pragma unroll
        for (int nt = 0; nt < 16; ++nt) {
            short8 vf = *reinterpret_cast<const short8*>(vb + (size_t)nt * 16 * TT);
            racc[nt] = __builtin_amdgcn_mfma_f32_16x16x32_bf16(pf, vf, racc[nt], 0, 0, 0);
        }
    }

    for (int w = 0; w < 4; ++w) {
        if (wid == w) {
            #pragma unroll
            for (int nt = 0; nt < 16; ++nt)
                #pragma unroll
                for (int r = 0; r < 4; ++r) {
                    int row = tl + r, col = nt * 16 + (lane & 15);
                    if (w == 0) red[row][col] = racc[nt][r];
                    else        red[row][col] += racc[nt][r];
                }
        }
        __syncthreads();
    }

    {
        int row = tid >> 4, c0 = (tid & 15) * 16;
        ushort8 lo, hi;
        #pragma unroll
        for (int j = 0; j < 8; ++j) lo[j] = f2bs(red[row][c0 + j]);
        #pragma unroll
        for (int j = 0; j < 8; ++j) hi[j] = f2bs(red[row][c0 + 8 + j]);
        unsigned short* dst = rout + (size_t)(b * TT + t0 + row) * ldr + c0;
        *reinterpret_cast<ushort8*>(dst)     = lo;
        *reinterpret_cast<ushort8*>(dst + 8) = hi;
    }
}

// ---------------------------------------------------------------------------
// Suffix scan over chunk states, both bands: grid (64, B, 2).
__global__ void scan_states2(const float* __restrict__ Gs, const float* __restrict__ Gf,
                             const float* __restrict__ dls, const float* __restrict__ dlf,
                             unsigned short* __restrict__ STs, unsigned short* __restrict__ STf) {
    int sel = blockIdx.z;
    const float* G = sel ? Gf : Gs;
    unsigned short* ST = sel ? STf : STs;
    float d = sigm(sel ? dlf[0] : dls[0]);
    int b = blockIdx.y;
    int e0 = (blockIdx.x * 256 + threadIdx.x) * 4;
    float dL = exp2f(log2f(d) * 128.f);
    float4 s = {0.f, 0.f, 0.f, 0.f};
    int i = e0 >> 8, j0 = e0 & 255;
    for (int c = 15; c >= 1; --c) {
        float4 g = *reinterpret_cast<const float4*>(G + (((size_t)(b * 16 + c)) << 16) + e0);
        s.x = g.x + dL * s.x; s.y = g.y + dL * s.y;
        s.z = g.z + dL * s.z; s.w = g.w + dL * s.w;
        unsigned short* dst = ST + (((size_t)(b * 15 + c - 1)) << 16);
        dst[(j0 + 0) * 256 + i] = f2bs(s.x);
        dst[(j0 + 1) * 256 + i] = f2bs(s.y);
        dst[(j0 + 2) * 256 + i] = f2bs(s.z);
        dst[(j0 + 3) * 256 + i] = f2bs(s.w);
    }
}

// ---------------------------------------------------------------------------
extern "C" void kernel_launch(void* const* d_in, const int* in_sizes, int n_in,
                              void* d_out, int out_size, void* d_ws, size_t ws_size,
                              hipStream_t stream) {
    (void)in_sizes; (void)n_in; (void)out_size; (void)ws_size;
    const float* x          = (const float*)d_in[0];
    const float* basis_low  = (const float*)d_in[1];
    const float* basis_mid  = (const float*)d_in[2];
    const float* basis_high = (const float*)d_in[3];
    const float* slow_q = (const float*)d_in[4];
    const float* slow_k = (const float*)d_in[5];
    const float* slow_v = (const float*)d_in[6];
    const float* slow_o = (const float*)d_in[7];
    const float* slow_decay = (const float*)d_in[8];
    const float* slow_scale = (const float*)d_in[9];
    const float* fast_q = (const float*)d_in[10];
    const float* fast_k = (const float*)d_in[11];
    const float* fast_v = (const float*)d_in[12];
    const float* fast_o = (const float*)d_in[13];
    const float* fast_decay = (const float*)d_in[14];
    const float* fast_scale = (const float*)d_in[15];
    const float* low_read  = (const float*)d_in[16];
    const float* low_write = (const float*)d_in[17];
    const float* low_mix   = (const float*)d_in[18];
    const float* low_bias  = (const float*)d_in[19];
    const float* low_oscale= (const float*)d_in[20];
    const float* mid_read  = (const float*)d_in[21];
    const float* mid_write = (const float*)d_in[22];
    const float* mid_mix   = (const float*)d_in[23];
    const float* mid_bias  = (const float*)d_in[24];
    const float* mid_oscale= (const float*)d_in[25];
    const float* high_read  = (const float*)d_in[26];
    const float* high_write = (const float*)d_in[27];
    const float* high_mix   = (const float*)d_in[28];
    const float* high_bias  = (const float*)d_in[29];
    const float* high_oscale= (const float*)d_in[30];
    const float* tg_w    = (const float*)d_in[31];
    const float* tg_b    = (const float*)d_in[32];
    const float* alpha_w = (const float*)d_in[33];
    const float* alpha_b = (const float*)d_in[34];
    const float* mem_slow_scale = (const float*)d_in[35];
    const float* mem_fast_scale = (const float*)d_in[36];
    const float* op_low_scale   = (const float*)d_in[37];
    const float* op_mid_scale   = (const float*)d_in[38];
    const float* op_high_scale  = (const float*)d_in[39];
    float* out = (float*)d_out;

    char* ws = (char*)d_ws;
    size_t off = 0;
    auto alloc = [&](size_t n) { char* p = ws + off; off += (n + 255) & ~(size_t)255; return p; };
    unsigned short* WT_p1   = (unsigned short*)alloc((size_t)6 * CC * VV * 2);   // [1536][1024]
    unsigned short* WT_read = (unsigned short*)alloc((size_t)3 * CC * VV * 2);   // [768][1024]
    unsigned short* Wcat_o  = (unsigned short*)alloc((size_t)VV * 512 * 2);
    unsigned short* Wcat_w  = (unsigned short*)alloc((size_t)VV * 768 * 2);
    unsigned short* WT_mix  = (unsigned short*)alloc((size_t)3 * 65536 * 2);
    unsigned short* WT_tg   = (unsigned short*)alloc((size_t)65536 * 2);
    unsigned short* WT_al   = (unsigned short*)alloc((size_t)65536 * 2);
    unsigned short* bb_low  = (unsigned short*)alloc((size_t)VV * 32 * 2);
    unsigned short* bb_mid  = (unsigned short*)alloc((size_t)VV * 64 * 2);
    unsigned short* bb_high = (unsigned short*)alloc((size_t)VV * 128 * 2);
    unsigned short* cqkv_l  = (unsigned short*)alloc((size_t)768 * 32 * 2);
    unsigned short* cqkv_h  = (unsigned short*)alloc((size_t)768 * 128 * 2);
    unsigned short* crd_l   = (unsigned short*)alloc((size_t)256 * 32 * 2);
    unsigned short* crd_m   = (unsigned short*)alloc((size_t)256 * 64 * 2);
    unsigned short* crd_h   = (unsigned short*)alloc((size_t)256 * 128 * 2);
    unsigned short* cO_s    = (unsigned short*)alloc((size_t)256 * 32 * 2);
    unsigned short* cO_f    = (unsigned short*)alloc((size_t)256 * 128 * 2);
    unsigned short* cW_l    = (unsigned short*)alloc((size_t)256 * 32 * 2);
    unsigned short* cW_m    = (unsigned short*)alloc((size_t)256 * 64 * 2);
    unsigned short* cW_h    = (unsigned short*)alloc((size_t)256 * 128 * 2);
    unsigned short* xn      = (unsigned short*)alloc((size_t)MR * VV * 2);       // reused: Gs, ph2 xn
    unsigned short* qkv     = (unsigned short*)alloc((size_t)MR * 1536 * 2);
    unsigned short* vt_s    = (unsigned short*)alloc((size_t)BB * CC * TT * 2);
    unsigned short* vt_f    = (unsigned short*)alloc((size_t)BB * CC * TT * 2);
    unsigned short* kts_s   = (unsigned short*)alloc((size_t)BB * CC * TT * 2);
    unsigned short* kts_f   = (unsigned short*)alloc((size_t)BB * CC * TT * 2);
    unsigned short* ST_s    = (unsigned short*)alloc((size_t)BB * 15 * 65536 * 2);
    unsigned short* ST_f    = (unsigned short*)alloc((size_t)BB * 15 * 65536 * 2);
    unsigned short* rcat    = (unsigned short*)alloc((size_t)MR * 512 * 2);
    unsigned short* rfast   = (unsigned short*)alloc((size_t)MR * CC * 2);
    unsigned short* hhigh   = (unsigned short*)alloc((size_t)MR * CC * 2);
    // overlays
    float* Gs = (float*)xn;                              // 64 states fp32 = 16.7MB
    float* Gf = (float*)rcat;                            // 64 states fp32 (rcat written later)
    unsigned short* z    = qkv;
    unsigned short* hcat = qkv + (size_t)MR * 768;

    // ---- weight prep: casts ----
    {
        CastArgs ca;
        int i = 0;
        auto J = [&](const float* s, unsigned short* d, int n) { ca.j[i].src = s; ca.j[i].dst = d; ca.j[i].n = n; ++i; };
        J(basis_low,  bb_low,  VV * 32);
        J(basis_mid,  bb_mid,  VV * 64);
        J(basis_high, bb_high, VV * 128);
        J(slow_q, cqkv_l + 0 * 256 * 32, 256 * 32);
        J(slow_k, cqkv_l + 1 * 256 * 32, 256 * 32);
        J(slow_v, cqkv_l + 2 * 256 * 32, 256 * 32);
        J(fast_q, cqkv_h + 0 * 256 * 128, 256 * 128);
        J(fast_k, cqkv_h + 1 * 256 * 128, 256 * 128);
        J(fast_v, cqkv_h + 2 * 256 * 128, 256 * 128);
        J(low_read,  crd_l, 256 * 32);
        J(mid_read,  crd_m, 256 * 64);
        J(high_read, crd_h, 256 * 128);
        J(slow_o,    cO_s,  256 * 32);
        J(fast_o,    cO_f,  256 * 128);
        J(low_write, cW_l,  256 * 32);
        J(mid_write, cW_m,  256 * 64);
        J(high_write,cW_h,  256 * 128);
        cast_bf16_multi<<<dim3(17, 64), 256, 0, stream>>>(ca);
    }

    // ---- softmax-weight logits (5 jobs, 1 launch), then row softmax ----
    {
        MJobs5 js;
        auto S = [&](int i, const unsigned short* A, int lda, const unsigned short* B, int K,
                     unsigned short* o, int nb) {
            js.j[i].A = A; js.j[i].Bt = B; js.j[i].outb = o; js.j[i].s1 = nullptr; js.j[i].s2 = nullptr;
            js.j[i].lda = lda; js.j[i].ldb = K; js.j[i].K = K; js.j[i].ldo = VV; js.j[i].gx = 16; js.j[i].nblk = nb;
        };
        S(0, cqkv_l, 32,  bb_low,  32,  WT_p1,                    192);
        S(1, cqkv_h, 128, bb_high, 128, WT_p1 + (size_t)768 * VV, 192);
        S(2, crd_l,  32,  bb_low,  32,  WT_read,                   64);
        S(3, crd_m,  64,  bb_mid,  64,  WT_read + (size_t)256 * VV, 64);
        S(4, crd_h,  128, bb_high, 128, WT_read + (size_t)512 * VV, 64);
        gemm_multi_k<0><<<576, 256, 0, stream>>>(js);
    }
    softmax_rows<<<2304, 256, 0, stream>>>(WT_p1);

    // ---- projection weights (5 jobs, 1 launch) ----
    {
        MJobs5 js;
        auto S = [&](int i, const unsigned short* A, int lda, const unsigned short* B, int K,
                     unsigned short* o, int ldo, const float* s1, const float* s2) {
            js.j[i].A = A; js.j[i].Bt = B; js.j[i].outb = o; js.j[i].s1 = s1; js.j[i].s2 = s2;
            js.j[i].lda = lda; js.j[i].ldb = K; js.j[i].K = K; js.j[i].ldo = ldo; js.j[i].gx = 4; js.j[i].nblk = 64;
        };
        S(0, bb_low,  32,  cO_s, 32,  Wcat_o,       512, slow_scale,  mem_slow_scale);
        S(1, bb_high, 128, cO_f, 128, Wcat_o + 256, 512, fast_scale,  mem_fast_scale);
        S(2, bb_low,  32,  cW_l, 32,  Wcat_w,       768, low_oscale,  op_low_scale);
        S(3, bb_mid,  64,  cW_m, 64,  Wcat_w + 256, 768, mid_oscale,  op_mid_scale);
        S(4, bb_high, 128, cW_h, 128, Wcat_w + 512, 768, high_oscale, op_high_scale);
        gemm_multi_k<4><<<320, 256, 0, stream>>>(js);
    }

    prep_T5<<<dim3(256, 5), 256, 0, stream>>>(tg_w, alpha_w, low_mix, mid_mix, high_mix,
                                              WT_tg, WT_al, WT_mix, WT_mix + 65536, WT_mix + 131072);

    // ---- phase 1 ----
    rmsnorm_k<<<MR, 256, 0, stream>>>(x, xn);
    { EpiP ep{}; ep.outb = qkv; ep.ldo = 1536;
      gemm128_k<0><<<dim3(12, 64), 256, 0, stream>>>(xn, 1024, WT_p1, 1024, 1024, ep); }
    transpose4_k<<<dim3(64, 8, 16), 256, 0, stream>>>(qkv, vt_s, vt_f, kts_s, kts_f, slow_decay, fast_decay);
    gstate_k<<<dim3(4, 4, 128), 256, 0, stream>>>(kts_s, vt_s, kts_f, vt_f, Gs, Gf);
    scan_states2<<<dim3(64, 4, 2), 256, 0, stream>>>(Gs, Gf, slow_decay, fast_decay, ST_s, ST_f);
    attn_k<<<dim3(512, 2), 256, 0, stream>>>(qkv, vt_s, vt_f, slow_decay, fast_decay, rcat, rfast);
    inter_k<<<dim3(4, 2, 120), 256, 0, stream>>>(qkv, ST_s, ST_f, slow_decay, fast_decay, rcat, rfast);
    sig_k<<<dim3(4, 128), 256, 0, stream>>>(rcat, 512, WT_tg, tg_b, rfast, 256, rcat, 512, 256);
    { EpiP ep{}; ep.outf = out; ep.addf = x; ep.ldo = 1024;
      gemm128_k<3><<<dim3(8, 64), 256, 0, stream>>>(rcat, 512, Wcat_o, 512, 512, ep); }

    // ---- phase 2 ----
    rmsnorm_k<<<MR, 256, 0, stream>>>(out, xn);
    { EpiP ep{}; ep.outb = z; ep.ldo = 768;
      gemm128_k<0><<<dim3(6, 64), 256, 0, stream>>>(xn, 1024, WT_read, 1024, 1024, ep); }
    gelu3_k<<<dim3(4, 128, 3), 256, 0, stream>>>(z, WT_mix, low_bias, mid_bias, high_bias, hcat, hhigh);
    sig_k<<<dim3(4, 128), 256, 0, stream>>>(hcat, 768, WT_al, alpha_b, hhigh, 256, hcat, 768, 512);
    { EpiP ep{}; ep.outf = out; ep.addf = out; ep.ldo = 1024;
      gemm128_k<3><<<dim3(6, 64), 256, 0, stream>>>(hcat, 768, Wcat_w, 768, 768, ep); }
}

// Round 9
// 274.030 us; speedup vs baseline: 1.1944x; 1.1944x over previous
//
#include <hip/hip_runtime.h>
#include <math.h>

#define BB 4
#define TT 2048
#define VV 1024
#define CC 256
#define MR (BB*TT)   // 8192 rows

using short8  = __attribute__((ext_vector_type(8))) short;
using ushort8 = __attribute__((ext_vector_type(8))) unsigned short;
using f32x4   = __attribute__((ext_vector_type(4))) float;

__device__ __forceinline__ float bs2f(unsigned short s) {
    return __uint_as_float(((unsigned int)s) << 16);
}
__device__ __forceinline__ unsigned short f2bs(float f) {
    unsigned int u = __float_as_uint(f);
    u += 0x7fffu + ((u >> 16) & 1u);          // round-to-nearest-even
    return (unsigned short)(u >> 16);
}
__device__ __forceinline__ void gl_lds16(const void* g, void* l) {
    __builtin_amdgcn_global_load_lds(
        (const __attribute__((address_space(1))) unsigned int*)g,
        (__attribute__((address_space(3))) unsigned int*)l, 16, 0, 0);
}
__device__ __forceinline__ float sigm(float x) { return 1.f / (1.f + expf(-x)); }

// ---------------------------------------------------------------------------
// Fused multi-array fp32 -> bf16 cast (coalesced). grid = (njobs, 64)
struct CastJob { const float* src; unsigned short* dst; int n; };
struct CastArgs { CastJob j[17]; };

__global__ void cast_bf16_multi(CastArgs a) {
    CastJob jb = a.j[blockIdx.x];
    int off = (blockIdx.y * 256 + threadIdx.x) * 8;
    if (off + 8 > jb.n) return;
    float4 v0 = *reinterpret_cast<const float4*>(jb.src + off);
    float4 v1 = *reinterpret_cast<const float4*>(jb.src + off + 4);
    ushort8 u;
    u[0] = f2bs(v0.x); u[1] = f2bs(v0.y); u[2] = f2bs(v0.z); u[3] = f2bs(v0.w);
    u[4] = f2bs(v1.x); u[5] = f2bs(v1.y); u[6] = f2bs(v1.z); u[7] = f2bs(v1.w);
    *reinterpret_cast<ushort8*>(jb.dst + off) = u;
}

// Row softmax in place over [rows][1024] bf16. grid = rows, block = 256.
__global__ void softmax_rows(unsigned short* __restrict__ w) {
    int r = blockIdx.x, t = threadIdx.x;
    unsigned short* row = w + (size_t)r * 1024;
    ushort4 u = reinterpret_cast<ushort4*>(row)[t];
    float v0 = bs2f(u.x), v1 = bs2f(u.y), v2 = bs2f(u.z), v3 = bs2f(u.w);
    __shared__ float red[256];
    red[t] = fmaxf(fmaxf(v0, v1), fmaxf(v2, v3));
    __syncthreads();
    for (int o = 128; o > 0; o >>= 1) { if (t < o) red[t] = fmaxf(red[t], red[t + o]); __syncthreads(); }
    float mx = red[0]; __syncthreads();
    float e0 = expf(v0 - mx), e1 = expf(v1 - mx), e2 = expf(v2 - mx), e3 = expf(v3 - mx);
    red[t] = e0 + e1 + e2 + e3;
    __syncthreads();
    for (int o = 128; o > 0; o >>= 1) { if (t < o) red[t] += red[t + o]; __syncthreads(); }
    float inv = 1.f / red[0];
    ushort4 o4;
    o4.x = f2bs(e0 * inv); o4.y = f2bs(e1 * inv); o4.z = f2bs(e2 * inv); o4.w = f2bs(e3 * inv);
    reinterpret_cast<ushort4*>(row)[t] = o4;
}

// 5x fused 256x256 fp32->bf16 transpose. grid = (256,5)
__global__ void prep_T5(const float* s0, const float* s1, const float* s2,
                        const float* s3, const float* s4,
                        unsigned short* d0, unsigned short* d1, unsigned short* d2,
                        unsigned short* d3, unsigned short* d4) {
    int y = blockIdx.y;
    const float* W = y == 0 ? s0 : y == 1 ? s1 : y == 2 ? s2 : y == 3 ? s3 : s4;
    unsigned short* WT = y == 0 ? d0 : y == 1 ? d1 : y == 2 ? d2 : y == 3 ? d3 : d4;
    int n = blockIdx.x, k = threadIdx.x;
    WT[(size_t)n * 256 + k] = f2bs(W[(size_t)k * 256 + n]);
}

// ---------------------------------------------------------------------------
// RMS norm: one block per row (V=1024), bf16 out
__global__ void rmsnorm_k(const float* __restrict__ x, unsigned short* __restrict__ xn) {
    int row = blockIdx.x, t = threadIdx.x;
    const float4 v = reinterpret_cast<const float4*>(x + (size_t)row * VV)[t];
    __shared__ float red[256];
    red[t] = v.x * v.x + v.y * v.y + v.z * v.z + v.w * v.w;
    __syncthreads();
    for (int o = 128; o > 0; o >>= 1) { if (t < o) red[t] += red[t + o]; __syncthreads(); }
    float r = rsqrtf(red[0] * (1.f / VV) + 1.1920929e-7f);
    ushort4 u;
    u.x = f2bs(v.x * r); u.y = f2bs(v.y * r); u.z = f2bs(v.z * r); u.w = f2bs(v.w * r);
    reinterpret_cast<ushort4*>(xn + (size_t)row * VV)[t] = u;
}

// ---------------------------------------------------------------------------
// 4-in-1 bf16 transpose of qkv slices: V^T (plain) and K^T (decay-scaled).
// grid (64, 8, 16): z -> (which = z>>2, b = z&3)
__global__ void transpose4_k(const unsigned short* __restrict__ qkv,
                             unsigned short* __restrict__ vt_s,
                             unsigned short* __restrict__ vt_f,
                             unsigned short* __restrict__ kts_s,
                             unsigned short* __restrict__ kts_f,
                             const float* __restrict__ dls,
                             const float* __restrict__ dlf) {
    __shared__ unsigned short tile[32][33];
    int z = blockIdx.z, b = z & 3, which = z >> 2;
    int srcoff = which == 0 ? 512 : which == 1 ? 1280 : which == 2 ? 256 : 1024;
    unsigned short* dst = which == 0 ? vt_s : which == 1 ? vt_f : which == 2 ? kts_s : kts_f;
    float l2d = 0.f;
    if (which == 2) l2d = log2f(sigm(dls[0]));
    if (which == 3) l2d = log2f(sigm(dlf[0]));
    int t0 = blockIdx.x * 32, c0 = blockIdx.y * 32;
    int tx = threadIdx.x & 31, ty = threadIdx.x >> 5;
    const unsigned short* src = qkv + srcoff;
    #pragma unroll
    for (int i = 0; i < 4; ++i) {
        int r = ty + i * 8;
        tile[r][tx] = src[(size_t)(b * TT + t0 + r) * 1536 + c0 + tx];
    }
    __syncthreads();
    float w = (which >= 2) ? exp2f(l2d * (float)((t0 + tx) & 127)) : 1.f;
    #pragma unroll
    for (int i = 0; i < 4; ++i) {
        int r = ty + i * 8;
        dst[((size_t)b * CC + c0 + r) * TT + t0 + tx] = f2bs(bs2f(tile[tx][r]) * w);
    }
}

// ---------------------------------------------------------------------------
// Shared 64x64 GEMM core: acc = A[m0..+64, :K] * Bt[n0..+64, :K]^T
__device__ __forceinline__ void gemm64_core(
    const unsigned short* A, int lda, const unsigned short* Bt, int ldb,
    int K, int m0, int n0, short8* As, short8* Bs, f32x4 (&acc)[2][2]) {
    const int tid = threadIdx.x;
    const int lane = tid & 63, wid = tid >> 6;
    const int wm = wid >> 1, wn = wid & 1;
    const int lrow = tid >> 2, lch = tid & 3;
    const int sws = lch ^ ((lrow >> 1) & 3);
    const unsigned short* ag = A + (size_t)(m0 + lrow) * lda + lch * 8;
    const unsigned short* bg = Bt + (size_t)(n0 + lrow) * ldb + lch * 8;
    #pragma unroll
    for (int i = 0; i < 2; ++i)
        #pragma unroll
        for (int j = 0; j < 2; ++j) acc[i][j] = {0.f, 0.f, 0.f, 0.f};
    const int g = lane >> 4;
    const int ra0 = wm * 32 + (lane & 15);
    const int rb0 = wn * 32 + (lane & 15);
    for (int k0 = 0; k0 < K; k0 += 32) {
        As[lrow * 4 + sws] = *reinterpret_cast<const short8*>(ag + k0);
        Bs[lrow * 4 + sws] = *reinterpret_cast<const short8*>(bg + k0);
        __syncthreads();
        short8 af[2], bf[2];
        #pragma unroll
        for (int i = 0; i < 2; ++i) {
            int ra = ra0 + i * 16;
            af[i] = As[ra * 4 + (g ^ ((ra >> 1) & 3))];
            int rb = rb0 + i * 16;
            bf[i] = Bs[rb * 4 + (g ^ ((rb >> 1) & 3))];
        }
        #pragma unroll
        for (int i = 0; i < 2; ++i)
            #pragma unroll
            for (int j = 0; j < 2; ++j)
                acc[i][j] = __builtin_amdgcn_mfma_f32_16x16x32_bf16(af[i], bf[j], acc[i][j], 0, 0, 0);
        __syncthreads();
    }
}

// epilogue index helpers (per thread)
#define EPI_LOOP(MV, NV, VV_, BODY)                                            \
    {   const int lane_ = threadIdx.x & 63, wid_ = threadIdx.x >> 6;           \
        const int wm_ = wid_ >> 1, wn_ = wid_ & 1;                             \
        _Pragma("unroll")                                                      \
        for (int i_ = 0; i_ < 2; ++i_)                                         \
        { _Pragma("unroll")                                                    \
          for (int j_ = 0; j_ < 2; ++j_)                                       \
          { _Pragma("unroll")                                                  \
            for (int r_ = 0; r_ < 4; ++r_)                                     \
            { int MV = m0 + wm_ * 32 + i_ * 16 + (lane_ >> 4) * 4 + r_;        \
              int NV = n0 + wn_ * 32 + j_ * 16 + (lane_ & 15);                 \
              float VV_ = acc[i_][j_][r_];                                     \
              BODY } } } }

// ---------------------------------------------------------------------------
// Multi-job 64^2 GEMM. EPI 0: plain bf16 store; 4: scaled bf16 store.
struct MJob {
    const unsigned short* A; const unsigned short* Bt; unsigned short* outb;
    const float* s1; const float* s2;
    int lda, ldb, K, ldo, gx, nblk;
};
struct MJobs5 { MJob j[5]; };

template<int EPI>
__global__ __launch_bounds__(256)
void gemm_multi_k(MJobs5 js) {
    int bid = blockIdx.x, ji = 0, base = 0;
    while (bid >= base + js.j[ji].nblk) { base += js.j[ji].nblk; ++ji; }
    MJob jb = js.j[ji];
    int rem = bid - base;
    int m0 = (rem / jb.gx) * 64, n0 = (rem % jb.gx) * 64;
    __shared__ short8 As[256], Bs[256];
    f32x4 acc[2][2];
    gemm64_core(jb.A, jb.lda, jb.Bt, jb.ldb, jb.K, m0, n0, As, Bs, acc);
    float sc = 1.f;
    if constexpr (EPI == 4) sc = jb.s1[0] * jb.s2[0];
    EPI_LOOP(m, n, v, { jb.outb[(size_t)m * jb.ldo + n] = f2bs(v * sc); })
}

// sigmoid(acc+bias)*aux epilogue GEMM (K=256, ldb=256). grid (4,128)
__global__ __launch_bounds__(256)
void sig_k(const unsigned short* A, int lda, const unsigned short* Bt,
           const float* bias, const unsigned short* aux, int ldaux,
           unsigned short* outb, int ldo, int coloff) {
    int m0 = blockIdx.y * 64, n0 = blockIdx.x * 64;
    __shared__ short8 As[256], Bs[256];
    f32x4 acc[2][2];
    gemm64_core(A, lda, Bt, 256, 256, m0, n0, As, Bs, acc);
    EPI_LOOP(m, n, v, {
        float s = sigm(v + bias[n]);
        float a = bs2f(aux[(size_t)m * ldaux + n]);
        outb[(size_t)m * ldo + coloff + n] = f2bs(s * a);
    })
}

// 3x gelu(z@mix+bias) batched over z. grid (4,128,3)
__global__ __launch_bounds__(256)
void gelu3_k(const unsigned short* zbuf, const unsigned short* WT_mix,
             const float* lb, const float* mb, const float* hb,
             unsigned short* hcat, unsigned short* hhigh) {
    int zi = blockIdx.z;
    const unsigned short* A = zbuf + zi * 256;
    const unsigned short* Bt = WT_mix + (size_t)zi * 65536;
    const float* bias = zi == 0 ? lb : zi == 1 ? mb : hb;
    unsigned short* outb = zi == 2 ? hhigh : hcat;
    int ldo = zi == 2 ? 256 : 768;
    int coloff = zi == 1 ? 256 : 0;
    int m0 = blockIdx.y * 64, n0 = blockIdx.x * 64;
    __shared__ short8 As[256], Bs[256];
    f32x4 acc[2][2];
    gemm64_core(A, 768, Bt, 256, 256, m0, n0, As, Bs, acc);
    EPI_LOOP(m, n, v, {
        float z = v + bias[n];
        float h = 0.5f * z * (1.f + erff(z * 0.70710678118654752f));
        outb[(size_t)m * ldo + coloff + n] = f2bs(h);
    })
}

// chunk states G^T = V^T @ (scaled K) per (b,chunk,band). grid (4,4,128)
// NOTE: A/B swapped vs the math (A=V^T, B=K̃^T) so G is stored TRANSPOSED:
// G'[j][i] = sum_t V[t][j] K̃[t][i]. This makes the suffix scan elementwise
// in the exact flat layout ST[j][i] that inter_k consumes (no scatter).
__global__ __launch_bounds__(256)
void gstate_k(const unsigned short* kts_s, const unsigned short* vt_s,
              const unsigned short* kts_f, const unsigned short* vt_f,
              float* Gs, float* Gf) {
    int zz = blockIdx.z;
    int sel = zz >> 6, z2 = zz & 63;
    int zb = z2 >> 4, zp = z2 & 15;
    const unsigned short* A  = (sel ? vt_f  : vt_s)  + (size_t)(zb * CC) * TT + zp * 128;
    const unsigned short* Bt = (sel ? kts_f : kts_s) + (size_t)(zb * CC) * TT + zp * 128;
    float* G = (sel ? Gf : Gs) + (size_t)z2 * 65536;
    int m0 = blockIdx.y * 64, n0 = blockIdx.x * 64;
    __shared__ short8 As[256], Bs[256];
    f32x4 acc[2][2];
    gemm64_core(A, TT, Bt, TT, 128, m0, n0, As, Bs, acc);
    EPI_LOOP(m, n, v, { G[(size_t)m * 256 + n] = v; })
}

// inter-chunk: r += d^(127-m) * Q_chunk @ S. grid (4,2,120): z<60 slow.
__global__ __launch_bounds__(256)
void inter_k(const unsigned short* qkv,
             const unsigned short* ST_s, const unsigned short* ST_f,
             const float* dls, const float* dlf,
             unsigned short* rcat, unsigned short* rfast) {
    int zz = blockIdx.z;
    int sel = zz >= 60, z2 = sel ? zz - 60 : zz;
    int zb = z2 / 15, zp = z2 % 15;
    const unsigned short* A = qkv + (sel ? 768 : 0) + (size_t)(zb * TT + zp * 128) * 1536;
    const unsigned short* Bt = (sel ? ST_f : ST_s) + (size_t)z2 * 65536;
    unsigned short* outb = sel ? rfast : rcat;
    int ldo = sel ? 256 : 512;
    float l2d = log2f(sigm(sel ? dlf[0] : dls[0]));
    int m0 = blockIdx.y * 64, n0 = blockIdx.x * 64;
    __shared__ short8 As[256], Bs[256];
    f32x4 acc[2][2];
    gemm64_core(A, 1536, Bt, 256, 256, m0, n0, As, Bs, acc);
    EPI_LOOP(m, n, v, {
        float rs = exp2f(l2d * (float)(127 - m));
        size_t idx = (size_t)(zb * TT + zp * 128 + m) * ldo + n;
        outb[idx] = f2bs(bs2f(outb[idx]) + v * rs);
    })
}

// ---------------------------------------------------------------------------
// 128x128 GEMM, BK=64, global_load_lds, XCD-swizzled grid (ngw % 8 == 0).
// Single-buffered (round-7 known-good). EPI 0: bf16 store; 3: fp32 addf+acc.
struct EpiP {
    float* outf; const float* addf;
    unsigned short* outb; int ldo;
};

template<int EPI>
__global__ __launch_bounds__(256)
void gemm128_k(const unsigned short* __restrict__ A, int lda,
               const unsigned short* __restrict__ Bt, int ldb, int K, EpiP ep) {
    __shared__ short8 As[1024], Bs[1024];          // 128 rows x 8 chunks (64 cols)
    const int tid = threadIdx.x;
    const int lane = tid & 63, wid = tid >> 6;
    const int wm = wid >> 1, wn = wid & 1;

    int lin = blockIdx.y * gridDim.x + blockIdx.x;
    int ngw = gridDim.x * gridDim.y;
    int q8 = ngw >> 3;
    int sw = (lin & 7) * q8 + (lin >> 3);
    const int m0 = (sw / gridDim.x) * 128, n0 = (sw % gridDim.x) * 128;

    const int srow = lane >> 3, schk = (lane & 7) ^ srow;
    const unsigned short* ga = A + (size_t)(m0 + wid * 32 + srow) * lda + schk * 8;
    const unsigned short* gb = Bt + (size_t)(n0 + wid * 32 + srow) * ldb + schk * 8;
    short8* lA = &As[(wid * 32) * 8];
    short8* lB = &Bs[(wid * 32) * 8];

    const int fr = lane & 15, fg = lane >> 4;

    f32x4 acc[4][4];
    #pragma unroll
    for (int i = 0; i < 4; ++i)
        #pragma unroll
        for (int j = 0; j < 4; ++j) acc[i][j] = {0.f, 0.f, 0.f, 0.f};

    for (int k0 = 0; k0 < K; k0 += 64) {
        #pragma unroll
        for (int q = 0; q < 4; ++q) {
            gl_lds16(ga + (size_t)(q * 8) * lda + k0, lA + q * 64);
            gl_lds16(gb + (size_t)(q * 8) * ldb + k0, lB + q * 64);
        }
        __syncthreads();
        #pragma unroll
        for (int kk = 0; kk < 2; ++kk) {
            short8 af[4], bf[4];
            #pragma unroll
            for (int i = 0; i < 4; ++i) {
                int ra = wm * 64 + i * 16 + fr;
                af[i] = As[ra * 8 + ((kk * 4 + fg) ^ (ra & 7))];
                int rb = wn * 64 + i * 16 + fr;
                bf[i] = Bs[rb * 8 + ((kk * 4 + fg) ^ (rb & 7))];
            }
            #pragma unroll
            for (int i = 0; i < 4; ++i)
                #pragma unroll
                for (int j = 0; j < 4; ++j)
                    acc[i][j] = __builtin_amdgcn_mfma_f32_16x16x32_bf16(af[i], bf[j], acc[i][j], 0, 0, 0);
        }
        __syncthreads();
    }

    #pragma unroll
    for (int i = 0; i < 4; ++i) {
        #pragma unroll
        for (int j = 0; j < 4; ++j) {
            #pragma unroll
            for (int r = 0; r < 4; ++r) {
                int m = m0 + wm * 64 + i * 16 + fg * 4 + r;
                int n = n0 + wn * 64 + j * 16 + fr;
                float v = acc[i][j][r];
                if constexpr (EPI == 0) {
                    ep.outb[(size_t)m * ep.ldo + n] = f2bs(v);
                } else {
                    size_t idx = (size_t)m * ep.ldo + n;
                    ep.outf[idx] = ep.addf[idx] + v;
                }
            }
        }
    }
}

// ---------------------------------------------------------------------------
// Intra-chunk decay retrieval; slow (y=0) and fast (y=1) merged in one grid.
__global__ __launch_bounds__(256)
void attn_k(const unsigned short* __restrict__ qkv,
            const unsigned short* __restrict__ vt_s,
            const unsigned short* __restrict__ vt_f,
            const float* __restrict__ dls, const float* __restrict__ dlf,
            unsigned short* __restrict__ rcat, unsigned short* __restrict__ rfast) {
    int y = blockIdx.y;
    int qoff = y ? 768 : 0, koff = y ? 1024 : 256;
    const unsigned short* vt = y ? vt_f : vt_s;
    unsigned short* rout = y ? rfast : rcat;
    int ldr = y ? 256 : 512;
    float l2d = log2f(sigm(y ? dlf[0] : dls[0]));

    int blk = blockIdx.x;
    int b = blk >> 7;
    int t0 = (blk & 127) << 4;
    int tid = threadIdx.x;
    int lane = tid & 63, wid = tid >> 6;

    __shared__ short8 Pl[4][64];
    __shared__ float  red[16][260];

    short8 qf[8];
    const size_t rowq = (size_t)(b * TT + t0 + (lane & 15)) * 1536 + qoff + (lane >> 4) * 8;
    #pragma unroll
    for (int ch = 0; ch < 8; ++ch)
        qf[ch] = *reinterpret_cast<const short8*>(qkv + rowq + ch * 32);

    f32x4 racc[16];
    #pragma unroll
    for (int i = 0; i < 16; ++i) racc[i] = {0.f, 0.f, 0.f, 0.f};

    unsigned short* pb = reinterpret_cast<unsigned short*>(&Pl[wid][0]);

    int sBeg = t0 & ~31;
    int sEnd = (t0 & ~127) + 128;
    const int tl = (lane >> 4) * 4;

    for (int s0 = sBeg + wid * 32; s0 < sEnd; s0 += 128) {
        #pragma unroll
        for (int h = 0; h < 2; ++h) {
            f32x4 sacc = {0.f, 0.f, 0.f, 0.f};
            const unsigned short* kb =
                qkv + (size_t)(b * TT + s0 + h * 16 + (lane & 15)) * 1536 + koff + (lane >> 4) * 8;
            #pragma unroll
            for (int ch = 0; ch < 8; ++ch) {
                short8 kf = *reinterpret_cast<const short8*>(kb + ch * 32);
                sacc = __builtin_amdgcn_mfma_f32_16x16x32_bf16(qf[ch], kf, sacc, 0, 0, 0);
            }
            int scol = s0 + h * 16 + (lane & 15);
            #pragma unroll
            for (int r = 0; r < 4; ++r) {
                int trow = t0 + tl + r;
                int d = scol - trow;
                float w = (d > 0) ? exp2f(l2d * (float)(d - 1)) : 0.f;
                int prow = tl + r, pcol = h * 16 + (lane & 15);
                int swp = (pcol >> 3) ^ ((prow >> 1) & 3);
                pb[(prow * 4 + swp) * 8 + (pcol & 7)] = f2bs(sacc[r] * w);
            }
        }
        asm volatile("s_waitcnt lgkmcnt(0)" ::: "memory");
        __builtin_amdgcn_sched_barrier(0);
        short8 pf;
        { int prow = lane & 15; pf = Pl[wid][prow * 4 + ((lane >> 4) ^ ((prow >> 1) & 3))]; }
        const unsigned short* vb = vt + ((size_t)b * CC + (lane & 15)) * TT + s0 + (lane >> 4) * 8;
        #pragma unroll
        for (int nt = 0; nt < 16; ++nt) {
            short8 vf = *reinterpret_cast<const short8*>(vb + (size_t)nt * 16 * TT);
            racc[nt] = __builtin_amdgcn_mfma_f32_16x16x32_bf16(pf, vf, racc[nt], 0, 0, 0);
        }
    }

    for (int w = 0; w < 4; ++w) {
        if (wid == w) {
            #pragma unroll
            for (int nt = 0; nt < 16; ++nt)
                #pragma unroll
                for (int r = 0; r < 4; ++r) {
                    int row = tl + r, col = nt * 16 + (lane & 15);
                    if (w == 0) red[row][col] = racc[nt][r];
                    else        red[row][col] += racc[nt][r];
                }
        }
        __syncthreads();
    }

    {
        int row = tid >> 4, c0 = (tid & 15) * 16;
        ushort8 lo, hi;
        #pragma unroll
        for (int j = 0; j < 8; ++j) lo[j] = f2bs(red[row][c0 + j]);
        #pragma unroll
        for (int j = 0; j < 8; ++j) hi[j] = f2bs(red[row][c0 + 8 + j]);
        unsigned short* dst = rout + (size_t)(b * TT + t0 + row) * ldr + c0;
        *reinterpret_cast<ushort8*>(dst)     = lo;
        *reinterpret_cast<ushort8*>(dst + 8) = hi;
    }
}

// ---------------------------------------------------------------------------
// Elementwise suffix scan over transposed chunk states (G' = G^T layout):
// Ssuf[c] = G'[c] + d^128 * Ssuf[c+1]; ST[c-1] = bf16(Ssuf[c]).
// Fully coalesced: float4 read + ushort4 write at the same flat offset.
// grid (64, B, 2), block 256.
__global__ void scan_states2(const float* __restrict__ Gs, const float* __restrict__ Gf,
                             const float* __restrict__ dls, const float* __restrict__ dlf,
                             unsigned short* __restrict__ STs, unsigned short* __restrict__ STf) {
    int sel = blockIdx.z;
    const float* G = sel ? Gf : Gs;
    unsigned short* ST = sel ? STf : STs;
    float d = sigm(sel ? dlf[0] : dls[0]);
    int b = blockIdx.y;
    int e0 = (blockIdx.x * 256 + threadIdx.x) * 4;
    float dL = exp2f(log2f(d) * 128.f);
    float4 s = {0.f, 0.f, 0.f, 0.f};
    for (int c = 15; c >= 1; --c) {
        float4 g = *reinterpret_cast<const float4*>(G + (((size_t)(b * 16 + c)) << 16) + e0);
        s.x = g.x + dL * s.x; s.y = g.y + dL * s.y;
        s.z = g.z + dL * s.z; s.w = g.w + dL * s.w;
        ushort4 o;
        o.x = f2bs(s.x); o.y = f2bs(s.y); o.z = f2bs(s.z); o.w = f2bs(s.w);
        *reinterpret_cast<ushort4*>(ST + (((size_t)(b * 15 + c - 1)) << 16) + e0) = o;
    }
}

// ---------------------------------------------------------------------------
extern "C" void kernel_launch(void* const* d_in, const int* in_sizes, int n_in,
                              void* d_out, int out_size, void* d_ws, size_t ws_size,
                              hipStream_t stream) {
    (void)in_sizes; (void)n_in; (void)out_size; (void)ws_size;
    const float* x          = (const float*)d_in[0];
    const float* basis_low  = (const float*)d_in[1];
    const float* basis_mid  = (const float*)d_in[2];
    const float* basis_high = (const float*)d_in[3];
    const float* slow_q = (const float*)d_in[4];
    const float* slow_k = (const float*)d_in[5];
    const float* slow_v = (const float*)d_in[6];
    const float* slow_o = (const float*)d_in[7];
    const float* slow_decay = (const float*)d_in[8];
    const float* slow_scale = (const float*)d_in[9];
    const float* fast_q = (const float*)d_in[10];
    const float* fast_k = (const float*)d_in[11];
    const float* fast_v = (const float*)d_in[12];
    const float* fast_o = (const float*)d_in[13];
    const float* fast_decay = (const float*)d_in[14];
    const float* fast_scale = (const float*)d_in[15];
    const float* low_read  = (const float*)d_in[16];
    const float* low_write = (const float*)d_in[17];
    const float* low_mix   = (const float*)d_in[18];
    const float* low_bias  = (const float*)d_in[19];
    const float* low_oscale= (const float*)d_in[20];
    const float* mid_read  = (const float*)d_in[21];
    const float* mid_write = (const float*)d_in[22];
    const float* mid_mix   = (const float*)d_in[23];
    const float* mid_bias  = (const float*)d_in[24];
    const float* mid_oscale= (const float*)d_in[25];
    const float* high_read  = (const float*)d_in[26];
    const float* high_write = (const float*)d_in[27];
    const float* high_mix   = (const float*)d_in[28];
    const float* high_bias  = (const float*)d_in[29];
    const float* high_oscale= (const float*)d_in[30];
    const float* tg_w    = (const float*)d_in[31];
    const float* tg_b    = (const float*)d_in[32];
    const float* alpha_w = (const float*)d_in[33];
    const float* alpha_b = (const float*)d_in[34];
    const float* mem_slow_scale = (const float*)d_in[35];
    const float* mem_fast_scale = (const float*)d_in[36];
    const float* op_low_scale   = (const float*)d_in[37];
    const float* op_mid_scale   = (const float*)d_in[38];
    const float* op_high_scale  = (const float*)d_in[39];
    float* out = (float*)d_out;

    char* ws = (char*)d_ws;
    size_t off = 0;
    auto alloc = [&](size_t n) { char* p = ws + off; off += (n + 255) & ~(size_t)255; return p; };
    unsigned short* WT_p1   = (unsigned short*)alloc((size_t)6 * CC * VV * 2);   // [1536][1024]
    unsigned short* WT_read = (unsigned short*)alloc((size_t)3 * CC * VV * 2);   // [768][1024]
    unsigned short* Wcat_o  = (unsigned short*)alloc((size_t)VV * 512 * 2);
    unsigned short* Wcat_w  = (unsigned short*)alloc((size_t)VV * 768 * 2);
    unsigned short* WT_mix  = (unsigned short*)alloc((size_t)3 * 65536 * 2);
    unsigned short* WT_tg   = (unsigned short*)alloc((size_t)65536 * 2);
    unsigned short* WT_al   = (unsigned short*)alloc((size_t)65536 * 2);
    unsigned short* bb_low  = (unsigned short*)alloc((size_t)VV * 32 * 2);
    unsigned short* bb_mid  = (unsigned short*)alloc((size_t)VV * 64 * 2);
    unsigned short* bb_high = (unsigned short*)alloc((size_t)VV * 128 * 2);
    unsigned short* cqkv_l  = (unsigned short*)alloc((size_t)768 * 32 * 2);
    unsigned short* cqkv_h  = (unsigned short*)alloc((size_t)768 * 128 * 2);
    unsigned short* crd_l   = (unsigned short*)alloc((size_t)256 * 32 * 2);
    unsigned short* crd_m   = (unsigned short*)alloc((size_t)256 * 64 * 2);
    unsigned short* crd_h   = (unsigned short*)alloc((size_t)256 * 128 * 2);
    unsigned short* cO_s    = (unsigned short*)alloc((size_t)256 * 32 * 2);
    unsigned short* cO_f    = (unsigned short*)alloc((size_t)256 * 128 * 2);
    unsigned short* cW_l    = (unsigned short*)alloc((size_t)256 * 32 * 2);
    unsigned short* cW_m    = (unsigned short*)alloc((size_t)256 * 64 * 2);
    unsigned short* cW_h    = (unsigned short*)alloc((size_t)256 * 128 * 2);
    unsigned short* xn      = (unsigned short*)alloc((size_t)MR * VV * 2);       // reused: Gs, ph2 xn
    unsigned short* qkv     = (unsigned short*)alloc((size_t)MR * 1536 * 2);
    unsigned short* vt_s    = (unsigned short*)alloc((size_t)BB * CC * TT * 2);
    unsigned short* vt_f    = (unsigned short*)alloc((size_t)BB * CC * TT * 2);
    unsigned short* kts_s   = (unsigned short*)alloc((size_t)BB * CC * TT * 2);
    unsigned short* kts_f   = (unsigned short*)alloc((size_t)BB * CC * TT * 2);
    unsigned short* ST_s    = (unsigned short*)alloc((size_t)BB * 15 * 65536 * 2);
    unsigned short* ST_f    = (unsigned short*)alloc((size_t)BB * 15 * 65536 * 2);
    unsigned short* rcat    = (unsigned short*)alloc((size_t)MR * 512 * 2);
    unsigned short* rfast   = (unsigned short*)alloc((size_t)MR * CC * 2);
    unsigned short* hhigh   = (unsigned short*)alloc((size_t)MR * CC * 2);
    // overlays
    float* Gs = (float*)xn;                              // 64 states fp32 = 16.7MB
    float* Gf = (float*)rcat;                            // 64 states fp32 (rcat written later)
    unsigned short* z    = qkv;
    unsigned short* hcat = qkv + (size_t)MR * 768;

    // ---- weight prep: casts ----
    {
        CastArgs ca;
        int i = 0;
        auto J = [&](const float* s, unsigned short* d, int n) { ca.j[i].src = s; ca.j[i].dst = d; ca.j[i].n = n; ++i; };
        J(basis_low,  bb_low,  VV * 32);
        J(basis_mid,  bb_mid,  VV * 64);
        J(basis_high, bb_high, VV * 128);
        J(slow_q, cqkv_l + 0 * 256 * 32, 256 * 32);
        J(slow_k, cqkv_l + 1 * 256 * 32, 256 * 32);
        J(slow_v, cqkv_l + 2 * 256 * 32, 256 * 32);
        J(fast_q, cqkv_h + 0 * 256 * 128, 256 * 128);
        J(fast_k, cqkv_h + 1 * 256 * 128, 256 * 128);
        J(fast_v, cqkv_h + 2 * 256 * 128, 256 * 128);
        J(low_read,  crd_l, 256 * 32);
        J(mid_read,  crd_m, 256 * 64);
        J(high_read, crd_h, 256 * 128);
        J(slow_o,    cO_s,  256 * 32);
        J(fast_o,    cO_f,  256 * 128);
        J(low_write, cW_l,  256 * 32);
        J(mid_write, cW_m,  256 * 64);
        J(high_write,cW_h,  256 * 128);
        cast_bf16_multi<<<dim3(17, 64), 256, 0, stream>>>(ca);
    }

    // ---- softmax-weight logits (5 jobs, 1 launch), then row softmax ----
    {
        MJobs5 js;
        auto S = [&](int i, const unsigned short* A, int lda, const unsigned short* B, int K,
                     unsigned short* o, int nb) {
            js.j[i].A = A; js.j[i].Bt = B; js.j[i].outb = o; js.j[i].s1 = nullptr; js.j[i].s2 = nullptr;
            js.j[i].lda = lda; js.j[i].ldb = K; js.j[i].K = K; js.j[i].ldo = VV; js.j[i].gx = 16; js.j[i].nblk = nb;
        };
        S(0, cqkv_l, 32,  bb_low,  32,  WT_p1,                    192);
        S(1, cqkv_h, 128, bb_high, 128, WT_p1 + (size_t)768 * VV, 192);
        S(2, crd_l,  32,  bb_low,  32,  WT_read,                   64);
        S(3, crd_m,  64,  bb_mid,  64,  WT_read + (size_t)256 * VV, 64);
        S(4, crd_h,  128, bb_high, 128, WT_read + (size_t)512 * VV, 64);
        gemm_multi_k<0><<<576, 256, 0, stream>>>(js);
    }
    softmax_rows<<<2304, 256, 0, stream>>>(WT_p1);

    // ---- projection weights (5 jobs, 1 launch) ----
    {
        MJobs5 js;
        auto S = [&](int i, const unsigned short* A, int lda, const unsigned short* B, int K,
                     unsigned short* o, int ldo, const float* s1, const float* s2) {
            js.j[i].A = A; js.j[i].Bt = B; js.j[i].outb = o; js.j[i].s1 = s1; js.j[i].s2 = s2;
            js.j[i].lda = lda; js.j[i].ldb = K; js.j[i].K = K; js.j[i].ldo = ldo; js.j[i].gx = 4; js.j[i].nblk = 64;
        };
        S(0, bb_low,  32,  cO_s, 32,  Wcat_o,       512, slow_scale,  mem_slow_scale);
        S(1, bb_high, 128, cO_f, 128, Wcat_o + 256, 512, fast_scale,  mem_fast_scale);
        S(2, bb_low,  32,  cW_l, 32,  Wcat_w,       768, low_oscale,  op_low_scale);
        S(3, bb_mid,  64,  cW_m, 64,  Wcat_w + 256, 768, mid_oscale,  op_mid_scale);
        S(4, bb_high, 128, cW_h, 128, Wcat_w + 512, 768, high_oscale, op_high_scale);
        gemm_multi_k<4><<<320, 256, 0, stream>>>(js);
    }

    prep_T5<<<dim3(256, 5), 256, 0, stream>>>(tg_w, alpha_w, low_mix, mid_mix, high_mix,
                                              WT_tg, WT_al, WT_mix, WT_mix + 65536, WT_mix + 131072);

    // ---- phase 1 ----
    rmsnorm_k<<<MR, 256, 0, stream>>>(x, xn);
    { EpiP ep{}; ep.outb = qkv; ep.ldo = 1536;
      gemm128_k<0><<<dim3(12, 64), 256, 0, stream>>>(xn, 1024, WT_p1, 1024, 1024, ep); }
    transpose4_k<<<dim3(64, 8, 16), 256, 0, stream>>>(qkv, vt_s, vt_f, kts_s, kts_f, slow_decay, fast_decay);
    gstate_k<<<dim3(4, 4, 128), 256, 0, stream>>>(kts_s, vt_s, kts_f, vt_f, Gs, Gf);
    scan_states2<<<dim3(64, 4, 2), 256, 0, stream>>>(Gs, Gf, slow_decay, fast_decay, ST_s, ST_f);
    attn_k<<<dim3(512, 2), 256, 0, stream>>>(qkv, vt_s, vt_f, slow_decay, fast_decay, rcat, rfast);
    inter_k<<<dim3(4, 2, 120), 256, 0, stream>>>(qkv, ST_s, ST_f, slow_decay, fast_decay, rcat, rfast);
    sig_k<<<dim3(4, 128), 256, 0, stream>>>(rcat, 512, WT_tg, tg_b, rfast, 256, rcat, 512, 256);
    { EpiP ep{}; ep.outf = out; ep.addf = x; ep.ldo = 1024;
      gemm128_k<3><<<dim3(8, 64), 256, 0, stream>>>(rcat, 512, Wcat_o, 512, 512, ep); }

    // ---- phase 2 ----
    rmsnorm_k<<<MR, 256, 0, stream>>>(out, xn);
    { EpiP ep{}; ep.outb = z; ep.ldo = 768;
      gemm128_k<0><<<dim3(6, 64), 256, 0, stream>>>(xn, 1024, WT_read, 1024, 1024, ep); }
    gelu3_k<<<dim3(4, 128, 3), 256, 0, stream>>>(z, WT_mix, low_bias, mid_bias, high_bias, hcat, hhigh);
    sig_k<<<dim3(4, 128), 256, 0, stream>>>(hcat, 768, WT_al, alpha_b, hhigh, 256, hcat, 768, 512);
    { EpiP ep{}; ep.outf = out; ep.addf = out; ep.ldo = 1024;
      gemm128_k<3><<<dim3(6, 64), 256, 0, stream>>>(hcat, 768, Wcat_w, 768, 768, ep); }
}